// Round 1
// baseline (16984.375 us; speedup 1.0000x reference)
//
#include <hip/hip_runtime.h>
#include <hip/hip_bf16.h>
#include <math.h>

#define EDIM   1024
#define TSEQ   512
#define NBATCH 2
#define NHEAD  16
#define HDIM   64
#define NLAYER 24
#define VOCAB  8124
#define DFFDIM 2730
#define MTOK   (NBATCH*TSEQ)     // 1024 rows
#define NELEM  (MTOK*EDIM)       // 1048576
#define EPSF   1e-5f
#define SCALEF (1.0f/32.0f)      // 1/sqrt(EDIM)
#define NEGBIG (-1e30f)

// ---------------------------------------------------------------- embedding+PE
__global__ __launch_bounds__(256) void k_embed(const int* __restrict__ tok,
                                               const float* __restrict__ emb,
                                               float* __restrict__ x) {
  const int bt = blockIdx.x;          // 0..1023 = b*TSEQ + t
  const int t  = bt & (TSEQ - 1);
  const int tk = tok[bt];
  const float* er = emb + (size_t)tk * EDIM;
  float* xr = x + (size_t)bt * EDIM;
  for (int e = threadIdx.x * 4; e < EDIM; e += 256 * 4) {
    float4 v = *(const float4*)(er + e);
    float vv[4] = {v.x, v.y, v.z, v.w};
    float ou[4];
#pragma unroll
    for (int j = 0; j < 4; ++j) {
      int ee = e + j;
      int i2 = ee & ~1;
      float freq = expf(-(float)i2 * (9.210340371976184f / 1024.0f));
      float ang  = (float)t * freq;
      ou[j] = vv[j] + ((ee & 1) ? cosf(ang) : sinf(ang));
    }
    *(float4*)(xr + e) = make_float4(ou[0], ou[1], ou[2], ou[3]);
  }
}

// ---------------------------------------------------------------- global RMS
__global__ __launch_bounds__(256) void k_red1(const float* __restrict__ xin,
                                              float* __restrict__ part) {
  float s = 0.f;
  for (int i = (blockIdx.x * 256 + threadIdx.x) * 4; i < NELEM; i += 256 * 256 * 4) {
    float4 v = *(const float4*)(xin + i);
    s += v.x * v.x + v.y * v.y + v.z * v.z + v.w * v.w;
  }
#pragma unroll
  for (int o = 32; o > 0; o >>= 1) s += __shfl_down(s, o);
  __shared__ float sm[4];
  if ((threadIdx.x & 63) == 0) sm[threadIdx.x >> 6] = s;
  __syncthreads();
  if (threadIdx.x == 0) part[blockIdx.x] = sm[0] + sm[1] + sm[2] + sm[3];
}

__global__ __launch_bounds__(256) void k_red2(const float* __restrict__ part,
                                              float* __restrict__ scale) {
  float s = part[threadIdx.x];
#pragma unroll
  for (int o = 32; o > 0; o >>= 1) s += __shfl_down(s, o);
  __shared__ float sm[4];
  if ((threadIdx.x & 63) == 0) sm[threadIdx.x >> 6] = s;
  __syncthreads();
  if (threadIdx.x == 0) {
    float tot = sm[0] + sm[1] + sm[2] + sm[3];
    scale[0] = 1.0f / sqrtf(tot / (float)NELEM + EPSF);
  }
}

__global__ __launch_bounds__(256) void k_rms(const float* __restrict__ xin,
                                             const float* __restrict__ g,
                                             const float* __restrict__ scale,
                                             float* __restrict__ yout) {
  const float sc = scale[0];
  const int i = (blockIdx.x * 256 + threadIdx.x) * 4;
  float4 v  = *(const float4*)(xin + i);
  float4 gv = *(const float4*)(g + (i & (EDIM - 1)));
  float4 r;
  r.x = v.x * sc * gv.x; r.y = v.y * sc * gv.y;
  r.z = v.z * sc * gv.z; r.w = v.w * sc * gv.w;
  *(float4*)(yout + i) = r;
}

// ---------------------------------------------------------------- generic GEMM
// C[M,N] = A[M,K] @ W[K,N] + bias (+ res).  BM=BN=64, BK=16, 256 thr, 4x4/thr.
template <int RES>
__global__ __launch_bounds__(256) void k_gemm(const float* __restrict__ A,
                                              const float* __restrict__ Wm,
                                              const float* __restrict__ bias,
                                              const float* __restrict__ res,
                                              float* __restrict__ out,
                                              int M, int N, int K) {
  __shared__ __align__(16) float As[16][68];
  __shared__ __align__(16) float Ws[16][68];
  const int tid = threadIdx.x;
  const int m0 = blockIdx.y << 6, n0 = blockIdx.x << 6;
  const int arow = tid >> 2, akq = (tid & 3) << 2;
  const int wrow = tid >> 4, wn4 = (tid & 15) << 2;
  const int ty = tid >> 4, tx = tid & 15;
  const bool kvec = ((K & 3) == 0);
  const bool nvec = ((N & 3) == 0);
  float acc[4][4] = {};
  for (int k0 = 0; k0 < K; k0 += 16) {
    float a0 = 0, a1 = 0, a2 = 0, a3 = 0;
    {
      const float* ap = A + (size_t)(m0 + arow) * K + (k0 + akq);
      if (kvec && (k0 + akq + 3 < K)) {
        float4 v = *(const float4*)ap; a0 = v.x; a1 = v.y; a2 = v.z; a3 = v.w;
      } else {
        if (k0 + akq + 0 < K) a0 = ap[0];
        if (k0 + akq + 1 < K) a1 = ap[1];
        if (k0 + akq + 2 < K) a2 = ap[2];
        if (k0 + akq + 3 < K) a3 = ap[3];
      }
    }
    float b0 = 0, b1 = 0, b2 = 0, b3 = 0;
    {
      const int kk = k0 + wrow;
      if (kk < K) {
        const float* wp = Wm + (size_t)kk * N + (n0 + wn4);
        if (nvec && (n0 + wn4 + 3 < N)) {
          float4 v = *(const float4*)wp; b0 = v.x; b1 = v.y; b2 = v.z; b3 = v.w;
        } else {
          if (n0 + wn4 + 0 < N) b0 = wp[0];
          if (n0 + wn4 + 1 < N) b1 = wp[1];
          if (n0 + wn4 + 2 < N) b2 = wp[2];
          if (n0 + wn4 + 3 < N) b3 = wp[3];
        }
      }
    }
    As[akq + 0][arow] = a0; As[akq + 1][arow] = a1;
    As[akq + 2][arow] = a2; As[akq + 3][arow] = a3;
    *(float4*)&Ws[wrow][wn4] = make_float4(b0, b1, b2, b3);
    __syncthreads();
#pragma unroll
    for (int kk = 0; kk < 16; ++kk) {
      float4 av = *(const float4*)&As[kk][ty << 2];
      float4 bv = *(const float4*)&Ws[kk][tx << 2];
      acc[0][0] += av.x * bv.x; acc[0][1] += av.x * bv.y; acc[0][2] += av.x * bv.z; acc[0][3] += av.x * bv.w;
      acc[1][0] += av.y * bv.x; acc[1][1] += av.y * bv.y; acc[1][2] += av.y * bv.z; acc[1][3] += av.y * bv.w;
      acc[2][0] += av.z * bv.x; acc[2][1] += av.z * bv.y; acc[2][2] += av.z * bv.z; acc[2][3] += av.z * bv.w;
      acc[3][0] += av.w * bv.x; acc[3][1] += av.w * bv.y; acc[3][2] += av.w * bv.z; acc[3][3] += av.w * bv.w;
    }
    __syncthreads();
  }
#pragma unroll
  for (int i = 0; i < 4; ++i) {
    const int m = m0 + (ty << 2) + i;
#pragma unroll
    for (int j = 0; j < 4; ++j) {
      const int n = n0 + (tx << 2) + j;
      if (n < N) {
        float v = acc[i][j] + bias[n];
        if (RES) v += res[(size_t)m * N + n];
        out[(size_t)m * N + n] = v;
      }
    }
  }
}

// ---------------------------------------------------------------- QKV GEMM with scatter
__global__ __launch_bounds__(256) void k_gemm_qkv(const float* __restrict__ A,
                                                  const float* __restrict__ Wm,
                                                  const float* __restrict__ bias,
                                                  float* __restrict__ qb,
                                                  float* __restrict__ kb,
                                                  float* __restrict__ vb) {
  const int M = MTOK, N = 3 * EDIM, K = EDIM;
  __shared__ __align__(16) float As[16][68];
  __shared__ __align__(16) float Ws[16][68];
  const int tid = threadIdx.x;
  const int m0 = blockIdx.y << 6, n0 = blockIdx.x << 6;
  const int arow = tid >> 2, akq = (tid & 3) << 2;
  const int wrow = tid >> 4, wn4 = (tid & 15) << 2;
  const int ty = tid >> 4, tx = tid & 15;
  float acc[4][4] = {};
  for (int k0 = 0; k0 < K; k0 += 16) {
    float4 av4 = *(const float4*)(A + (size_t)(m0 + arow) * K + (k0 + akq));
    float4 wv4 = *(const float4*)(Wm + (size_t)(k0 + wrow) * N + (n0 + wn4));
    As[akq + 0][arow] = av4.x; As[akq + 1][arow] = av4.y;
    As[akq + 2][arow] = av4.z; As[akq + 3][arow] = av4.w;
    *(float4*)&Ws[wrow][wn4] = wv4;
    __syncthreads();
#pragma unroll
    for (int kk = 0; kk < 16; ++kk) {
      float4 av = *(const float4*)&As[kk][ty << 2];
      float4 bv = *(const float4*)&Ws[kk][tx << 2];
      acc[0][0] += av.x * bv.x; acc[0][1] += av.x * bv.y; acc[0][2] += av.x * bv.z; acc[0][3] += av.x * bv.w;
      acc[1][0] += av.y * bv.x; acc[1][1] += av.y * bv.y; acc[1][2] += av.y * bv.z; acc[1][3] += av.y * bv.w;
      acc[2][0] += av.z * bv.x; acc[2][1] += av.z * bv.y; acc[2][2] += av.z * bv.z; acc[2][3] += av.z * bv.w;
      acc[3][0] += av.w * bv.x; acc[3][1] += av.w * bv.y; acc[3][2] += av.w * bv.z; acc[3][3] += av.w * bv.w;
    }
    __syncthreads();
  }
  (void)M;
#pragma unroll
  for (int i = 0; i < 4; ++i) {
    const int m = m0 + (ty << 2) + i;
    const int b = m >> 9, t = m & (TSEQ - 1);
#pragma unroll
    for (int j = 0; j < 4; ++j) {
      const int c = n0 + (tx << 2) + j;
      const float v = acc[i][j] + bias[c];
      const int h = c / (3 * HDIM);
      const int r = (c >> 6) % 3;
      const int s = c & (HDIM - 1);
      float* dst = (r == 0) ? qb : (r == 1) ? kb : vb;
      dst[((size_t)(b * NHEAD + h) * TSEQ + t) * HDIM + s] = v;
    }
  }
}

// ---------------------------------------------------------------- fused W1/W3 SwiGLU GEMM
__global__ __launch_bounds__(256) void k_gemm_w13(const float* __restrict__ A,
                                                  const float* __restrict__ W1,
                                                  const float* __restrict__ W3,
                                                  const float* __restrict__ b1,
                                                  const float* __restrict__ b3,
                                                  float* __restrict__ u) {
  const int N = DFFDIM, K = EDIM;
  __shared__ __align__(16) float As[16][68];
  __shared__ __align__(16) float W1s[16][68];
  __shared__ __align__(16) float W3s[16][68];
  const int tid = threadIdx.x;
  const int m0 = blockIdx.y << 6, n0 = blockIdx.x << 6;
  const int arow = tid >> 2, akq = (tid & 3) << 2;
  const int wrow = tid >> 4, wn4 = (tid & 15) << 2;
  const int ty = tid >> 4, tx = tid & 15;
  float acc1[4][4] = {}, acc3[4][4] = {};
  for (int k0 = 0; k0 < K; k0 += 16) {
    float4 av4 = *(const float4*)(A + (size_t)(m0 + arow) * K + (k0 + akq));
    // W rows: N=2730 not 16B aligned per row -> scalar guarded loads
    float w1v[4] = {0, 0, 0, 0}, w3v[4] = {0, 0, 0, 0};
    {
      const size_t rowoff = (size_t)(k0 + wrow) * N;
#pragma unroll
      for (int j = 0; j < 4; ++j) {
        const int n = n0 + wn4 + j;
        if (n < N) {
          w1v[j] = W1[rowoff + n];
          w3v[j] = W3[rowoff + n];
        }
      }
    }
    As[akq + 0][arow] = av4.x; As[akq + 1][arow] = av4.y;
    As[akq + 2][arow] = av4.z; As[akq + 3][arow] = av4.w;
    *(float4*)&W1s[wrow][wn4] = make_float4(w1v[0], w1v[1], w1v[2], w1v[3]);
    *(float4*)&W3s[wrow][wn4] = make_float4(w3v[0], w3v[1], w3v[2], w3v[3]);
    __syncthreads();
#pragma unroll
    for (int kk = 0; kk < 16; ++kk) {
      float4 av = *(const float4*)&As[kk][ty << 2];
      float4 b1v = *(const float4*)&W1s[kk][tx << 2];
      float4 b3v = *(const float4*)&W3s[kk][tx << 2];
      acc1[0][0] += av.x * b1v.x; acc1[0][1] += av.x * b1v.y; acc1[0][2] += av.x * b1v.z; acc1[0][3] += av.x * b1v.w;
      acc1[1][0] += av.y * b1v.x; acc1[1][1] += av.y * b1v.y; acc1[1][2] += av.y * b1v.z; acc1[1][3] += av.y * b1v.w;
      acc1[2][0] += av.z * b1v.x; acc1[2][1] += av.z * b1v.y; acc1[2][2] += av.z * b1v.z; acc1[2][3] += av.z * b1v.w;
      acc1[3][0] += av.w * b1v.x; acc1[3][1] += av.w * b1v.y; acc1[3][2] += av.w * b1v.z; acc1[3][3] += av.w * b1v.w;
      acc3[0][0] += av.x * b3v.x; acc3[0][1] += av.x * b3v.y; acc3[0][2] += av.x * b3v.z; acc3[0][3] += av.x * b3v.w;
      acc3[1][0] += av.y * b3v.x; acc3[1][1] += av.y * b3v.y; acc3[1][2] += av.y * b3v.z; acc3[1][3] += av.y * b3v.w;
      acc3[2][0] += av.z * b3v.x; acc3[2][1] += av.z * b3v.y; acc3[2][2] += av.z * b3v.z; acc3[2][3] += av.z * b3v.w;
      acc3[3][0] += av.w * b3v.x; acc3[3][1] += av.w * b3v.y; acc3[3][2] += av.w * b3v.z; acc3[3][3] += av.w * b3v.w;
    }
    __syncthreads();
  }
#pragma unroll
  for (int i = 0; i < 4; ++i) {
    const int m = m0 + (ty << 2) + i;
#pragma unroll
    for (int j = 0; j < 4; ++j) {
      const int n = n0 + (tx << 2) + j;
      if (n < N) {
        const float a1 = acc1[i][j] + b1[n];
        const float a3 = acc3[i][j] + b3[n];
        const float sig = 1.0f / (1.0f + expf(-a1));
        u[(size_t)m * N + n] = a1 * sig * a3;
      }
    }
  }
}

// ---------------------------------------------------------------- attention QK^T (+mask+scale)
__global__ __launch_bounds__(256) void k_attn_qk(const float* __restrict__ qb,
                                                 const float* __restrict__ kb,
                                                 float* __restrict__ sc) {
  const int bh = blockIdx.z;
  const float* qp = qb + (size_t)bh * TSEQ * HDIM;
  const float* kp = kb + (size_t)bh * TSEQ * HDIM;
  float* sp = sc + (size_t)bh * TSEQ * TSEQ;
  const int tid = threadIdx.x;
  const int m0 = blockIdx.y << 6, n0 = blockIdx.x << 6;
  const int ty = tid >> 4, tx = tid & 15;
  if (n0 > m0 + 63) {  // fully masked tile
#pragma unroll
    for (int i = 0; i < 4; ++i) {
      const int m = m0 + (ty << 2) + i;
#pragma unroll
      for (int j = 0; j < 4; ++j) sp[(size_t)m * TSEQ + n0 + (tx << 2) + j] = NEGBIG;
    }
    return;
  }
  __shared__ __align__(16) float As[16][68];
  __shared__ __align__(16) float Ws[16][68];
  const int arow = tid >> 2, akq = (tid & 3) << 2;
  float acc[4][4] = {};
  for (int k0 = 0; k0 < HDIM; k0 += 16) {
    float4 av4 = *(const float4*)(qp + (size_t)(m0 + arow) * HDIM + (k0 + akq));
    float4 kv4 = *(const float4*)(kp + (size_t)(n0 + arow) * HDIM + (k0 + akq));
    As[akq + 0][arow] = av4.x; As[akq + 1][arow] = av4.y;
    As[akq + 2][arow] = av4.z; As[akq + 3][arow] = av4.w;
    Ws[akq + 0][arow] = kv4.x; Ws[akq + 1][arow] = kv4.y;
    Ws[akq + 2][arow] = kv4.z; Ws[akq + 3][arow] = kv4.w;
    __syncthreads();
#pragma unroll
    for (int kk = 0; kk < 16; ++kk) {
      float4 av = *(const float4*)&As[kk][ty << 2];
      float4 bv = *(const float4*)&Ws[kk][tx << 2];
      acc[0][0] += av.x * bv.x; acc[0][1] += av.x * bv.y; acc[0][2] += av.x * bv.z; acc[0][3] += av.x * bv.w;
      acc[1][0] += av.y * bv.x; acc[1][1] += av.y * bv.y; acc[1][2] += av.y * bv.z; acc[1][3] += av.y * bv.w;
      acc[2][0] += av.z * bv.x; acc[2][1] += av.z * bv.y; acc[2][2] += av.z * bv.z; acc[2][3] += av.z * bv.w;
      acc[3][0] += av.w * bv.x; acc[3][1] += av.w * bv.y; acc[3][2] += av.w * bv.z; acc[3][3] += av.w * bv.w;
    }
    __syncthreads();
  }
#pragma unroll
  for (int i = 0; i < 4; ++i) {
    const int m = m0 + (ty << 2) + i;
#pragma unroll
    for (int j = 0; j < 4; ++j) {
      const int n = n0 + (tx << 2) + j;
      sp[(size_t)m * TSEQ + n] = (n <= m) ? acc[i][j] * SCALEF : NEGBIG;
    }
  }
}

// ---------------------------------------------------------------- row softmax (512 wide)
__global__ __launch_bounds__(256) void k_softmax(float* __restrict__ sc) {
  const int row = blockIdx.x * 4 + (threadIdx.x >> 6);
  const int lane = threadIdx.x & 63;
  float* rp = sc + (size_t)row * TSEQ;
  float v[8];
  float mx = NEGBIG;
#pragma unroll
  for (int j = 0; j < 8; ++j) { v[j] = rp[lane + j * 64]; mx = fmaxf(mx, v[j]); }
#pragma unroll
  for (int o = 32; o > 0; o >>= 1) mx = fmaxf(mx, __shfl_xor(mx, o));
  float s = 0.f;
#pragma unroll
  for (int j = 0; j < 8; ++j) { v[j] = __expf(v[j] - mx); s += v[j]; }
#pragma unroll
  for (int o = 32; o > 0; o >>= 1) s += __shfl_xor(s, o);
  const float inv = 1.0f / s;
#pragma unroll
  for (int j = 0; j < 8; ++j) rp[lane + j * 64] = v[j] * inv;
}

// ---------------------------------------------------------------- attention P@V (causal-skip)
__global__ __launch_bounds__(256) void k_attn_pv(const float* __restrict__ sc,
                                                 const float* __restrict__ vb,
                                                 float* __restrict__ y2) {
  const int bh = blockIdx.z;
  const int b = bh >> 4, h = bh & 15;
  const float* sp = sc + (size_t)bh * TSEQ * TSEQ;
  const float* vp = vb + (size_t)bh * TSEQ * HDIM;
  __shared__ __align__(16) float As[16][68];
  __shared__ __align__(16) float Ws[16][68];
  const int tid = threadIdx.x;
  const int m0 = blockIdx.y << 6;
  const int arow = tid >> 2, akq = (tid & 3) << 2;
  const int wrow = tid >> 4, wn4 = (tid & 15) << 2;
  const int ty = tid >> 4, tx = tid & 15;
  float acc[4][4] = {};
  const int kmax = m0 + 64;  // p == 0 beyond the diagonal (exact)
  for (int k0 = 0; k0 < kmax; k0 += 16) {
    float4 av4 = *(const float4*)(sp + (size_t)(m0 + arow) * TSEQ + (k0 + akq));
    float4 wv4 = *(const float4*)(vp + (size_t)(k0 + wrow) * HDIM + wn4);
    As[akq + 0][arow] = av4.x; As[akq + 1][arow] = av4.y;
    As[akq + 2][arow] = av4.z; As[akq + 3][arow] = av4.w;
    *(float4*)&Ws[wrow][wn4] = wv4;
    __syncthreads();
#pragma unroll
    for (int kk = 0; kk < 16; ++kk) {
      float4 av = *(const float4*)&As[kk][ty << 2];
      float4 bv = *(const float4*)&Ws[kk][tx << 2];
      acc[0][0] += av.x * bv.x; acc[0][1] += av.x * bv.y; acc[0][2] += av.x * bv.z; acc[0][3] += av.x * bv.w;
      acc[1][0] += av.y * bv.x; acc[1][1] += av.y * bv.y; acc[1][2] += av.y * bv.z; acc[1][3] += av.y * bv.w;
      acc[2][0] += av.z * bv.x; acc[2][1] += av.z * bv.y; acc[2][2] += av.z * bv.z; acc[2][3] += av.z * bv.w;
      acc[3][0] += av.w * bv.x; acc[3][1] += av.w * bv.y; acc[3][2] += av.w * bv.z; acc[3][3] += av.w * bv.w;
    }
    __syncthreads();
  }
#pragma unroll
  for (int i = 0; i < 4; ++i) {
    const int m = m0 + (ty << 2) + i;   // = t
#pragma unroll
    for (int j = 0; j < 4; ++j) {
      const int n = (tx << 2) + j;      // = s
      y2[((size_t)(b * TSEQ) + m) * EDIM + h * HDIM + n] = acc[i][j];
    }
  }
}

// ---------------------------------------------------------------- launcher
extern "C" void kernel_launch(void* const* d_in, const int* in_sizes, int n_in,
                              void* d_out, int out_size, void* d_ws, size_t ws_size,
                              hipStream_t stream) {
  const int*   tokens  = (const int*)d_in[0];
  const float* emb     = (const float*)d_in[1];
  const float* Wqkv    = (const float*)d_in[2];
  const float* bqkv    = (const float*)d_in[3];
  const float* Wo      = (const float*)d_in[4];
  const float* bo      = (const float*)d_in[5];
  const float* W1      = (const float*)d_in[6];
  const float* b1      = (const float*)d_in[7];
  const float* W3      = (const float*)d_in[8];
  const float* b3      = (const float*)d_in[9];
  const float* W2      = (const float*)d_in[10];
  const float* b2      = (const float*)d_in[11];
  const float* g_mha   = (const float*)d_in[12];
  const float* g_ff    = (const float*)d_in[13];
  const float* g_final = (const float*)d_in[14];
  const float* Wout    = (const float*)d_in[15];
  const float* bout    = (const float*)d_in[16];
  float* out = (float*)d_out;

  float* ws = (float*)d_ws;
  const size_t M1 = 1u << 20;               // 1048576
  float* x    = ws;
  float* y    = ws + 1 * M1;
  float* qb   = ws + 2 * M1;
  float* kb   = ws + 3 * M1;
  float* vb   = ws + 4 * M1;
  float* y2   = ws + 5 * M1;
  float* big  = ws + 6 * M1;                // scores (8.39M f) / SwiGLU u (2.80M f)
  float* part = big + (size_t)32 * TSEQ * TSEQ;
  float* scal = part + 256;

  k_embed<<<MTOK, 256, 0, stream>>>(tokens, emb, x);

  for (int l = 0; l < NLAYER; ++l) {
    // --- MHA ---
    k_red1<<<256, 256, 0, stream>>>(x, part);
    k_red2<<<1, 256, 0, stream>>>(part, scal);
    k_rms<<<1024, 256, 0, stream>>>(x, g_mha + (size_t)l * EDIM, scal, y);
    k_gemm_qkv<<<dim3(48, 16), 256, 0, stream>>>(
        y, Wqkv + (size_t)l * EDIM * 3 * EDIM, bqkv + (size_t)l * 3 * EDIM, qb, kb, vb);
    k_attn_qk<<<dim3(8, 8, 32), 256, 0, stream>>>(qb, kb, big);
    k_softmax<<<4096, 256, 0, stream>>>(big);
    k_attn_pv<<<dim3(1, 8, 32), 256, 0, stream>>>(big, vb, y2);
    k_gemm<1><<<dim3(16, 16), 256, 0, stream>>>(
        y2, Wo + (size_t)l * EDIM * EDIM, bo + (size_t)l * EDIM, x, x, MTOK, EDIM, EDIM);
    // --- SwiGLU FFN ---
    k_red1<<<256, 256, 0, stream>>>(x, part);
    k_red2<<<1, 256, 0, stream>>>(part, scal);
    k_rms<<<1024, 256, 0, stream>>>(x, g_ff + (size_t)l * EDIM, scal, y);
    k_gemm_w13<<<dim3(43, 16), 256, 0, stream>>>(
        y, W1 + (size_t)l * EDIM * DFFDIM, W3 + (size_t)l * EDIM * DFFDIM,
        b1 + (size_t)l * DFFDIM, b3 + (size_t)l * DFFDIM, big);
    k_gemm<1><<<dim3(16, 16), 256, 0, stream>>>(
        big, W2 + (size_t)l * DFFDIM * EDIM, b2 + (size_t)l * EDIM, x, x, MTOK, EDIM, DFFDIM);
  }

  // --- final RMS + vocab head ---
  k_red1<<<256, 256, 0, stream>>>(x, part);
  k_red2<<<1, 256, 0, stream>>>(part, scal);
  k_rms<<<1024, 256, 0, stream>>>(x, g_final, scal, y);
  k_gemm<0><<<dim3(127, 16), 256, 0, stream>>>(
      y, Wout, bout, nullptr, out, MTOK, VOCAB, EDIM);
}